// Round 5
// baseline (102.765 us; speedup 1.0000x reference)
//
#include <hip/hip_runtime.h>

// RASP pairwise score, N=6144, P = N(N-1)/2.
// R5: parallel counting sort (hist 24 blocks w/ global atomics; scatter 24
// blocks, per-block LDS re-scan of the 86-bin hist, global atomic position).
// Pair kernel unchanged from R4: wave holds 16 j-atoms in lanes 0..15,
// v_readlane broadcast (j-side decode on SALU), 2 i-atoms/thread, pot slice
// staged in LDS, diagonal tiles templated.

#define T_TYPES 85
#define D_BINS 21
#define TSTRIDE (T_TYPES * D_BINS)            // 1785
#define KSTRIDE (T_TYPES * T_TYPES * D_BINS)  // 151725
#define INVALID_KEY 85
#define NKEYS 86
#define TILE 128
#define PTHREADS 512
#define MAXSLOTS 36

// ws layout: [0..343]   int hist[86]
//            [344..687] int counters[86]  (both zeroed by memsetAsync of 1KB)
//            [1024...]  float4 sorted[n]

__global__ void hist_kernel(const int* __restrict__ types, int n,
                            int* __restrict__ hist) {
    int i = blockIdx.x * blockDim.x + threadIdx.x;
    if (i < n) {
        int t = types[i];
        atomicAdd(&hist[(t < 0) ? INVALID_KEY : t], 1);
    }
}

__global__ void scatter_kernel(const float* __restrict__ coords,
                               const int* __restrict__ res_ids,
                               const int* __restrict__ types, int n,
                               const int* __restrict__ hist,
                               int* __restrict__ counters,
                               float4* __restrict__ sorted) {
    __shared__ int base[NKEYS];
    int tid = threadIdx.x;
    __shared__ int hl[NKEYS];
    if (tid < NKEYS) hl[tid] = hist[tid];
    __syncthreads();
    if (tid == 0) {
        int s = 0;
        for (int i = 0; i < NKEYS; ++i) { base[i] = s; s += hl[i]; }
    }
    __syncthreads();

    int i = blockIdx.x * blockDim.x + tid;
    if (i < n) {
        int t = types[i];
        int key = (t < 0) ? INVALID_KEY : t;
        int pos = base[key] + atomicAdd(&counters[key], 1);
        float4 v;
        if (t < 0) {
            v.x = 1.0e6f + 1000.0f * (float)pos;   // poison: dist >> 20 always
            v.y = 0.0f; v.z = 0.0f;
            v.w = __int_as_float((res_ids[i] << 7) | 84);
        } else {
            v.x = coords[3 * i + 0];
            v.y = coords[3 * i + 1];
            v.z = coords[3 * i + 2];
            v.w = __int_as_float((res_ids[i] << 7) | t);
        }
        sorted[pos] = v;
    }
}

__device__ __forceinline__ float bcastf(float v, int u) {
    return __int_as_float(__builtin_amdgcn_readlane(__float_as_int(v), u));
}

template <bool DIAG>
__device__ __forceinline__ void pair_body(const float4& jreg, const float4& m0, const float4& m1,
                                          const float* __restrict__ pot_s,
                                          int resi0, int resi1, int sb21_0, int sb21_1,
                                          int slots21, int tloj, int ntj,
                                          int jbase, int p0, int p1,
                                          float& acc0, float& acc1) {
#pragma unroll
    for (int u = 0; u < 16; ++u) {
        float ox = bcastf(jreg.x, u);
        float oy = bcastf(jreg.y, u);
        float oz = bcastf(jreg.z, u);
        int pw = __builtin_amdgcn_readlane(__float_as_int(jreg.w), u);
        int keyj = pw & 127;
        int resj = pw >> 7;
        int jslot = min(max(keyj - tloj, 0), ntj - 1);
        int jb = jslot * D_BINS;
        int q = jbase + u;

        {
            float dx = m0.x - ox, dy = m0.y - oy, dz = m0.z - oz;
            float dist = __builtin_amdgcn_sqrtf(dx * dx + dy * dy + dz * dz);
            int sep = abs(resi0 - resj);
            int k = min(max(sep - 1, 0), 5);
            int d0i = min((int)dist, 19);
            float alpha = dist - (float)d0i;
            int li = k * slots21 + sb21_0 + jb + d0i;
            float e0 = pot_s[li];
            float e1 = pot_s[li + 1];
            float val = __builtin_fmaf(alpha, e1 - e0, e0) - 2.7f;
            bool valid = (sep > 2) && (dist < 20.0f);
            if (DIAG) valid = valid && (q > p0);
            acc0 += valid ? val : 0.0f;
        }
        {
            float dx = m1.x - ox, dy = m1.y - oy, dz = m1.z - oz;
            float dist = __builtin_amdgcn_sqrtf(dx * dx + dy * dy + dz * dz);
            int sep = abs(resi1 - resj);
            int k = min(max(sep - 1, 0), 5);
            int d0i = min((int)dist, 19);
            float alpha = dist - (float)d0i;
            int li = k * slots21 + sb21_1 + jb + d0i;
            float e0 = pot_s[li];
            float e1 = pot_s[li + 1];
            float val = __builtin_fmaf(alpha, e1 - e0, e0) - 2.7f;
            bool valid = (sep > 2) && (dist < 20.0f);
            if (DIAG) valid = valid && (q > p1);
            acc1 += valid ? val : 0.0f;
        }
    }
}

template <bool DIAG>
__device__ __forceinline__ void pair_body_global(const float4& jreg, const float4& m0, const float4& m1,
                                                 const float* __restrict__ pot,
                                                 int resi0, int resi1, int tib0, int tib1,
                                                 int jbase, int p0, int p1,
                                                 float& acc0, float& acc1) {
#pragma unroll
    for (int u = 0; u < 16; ++u) {
        float ox = bcastf(jreg.x, u);
        float oy = bcastf(jreg.y, u);
        float oz = bcastf(jreg.z, u);
        int pw = __builtin_amdgcn_readlane(__float_as_int(jreg.w), u);
        int keyj = min(pw & 127, 84);
        int resj = pw >> 7;
        int jb = keyj * D_BINS;
        int q = jbase + u;
        {
            float dx = m0.x - ox, dy = m0.y - oy, dz = m0.z - oz;
            float dist = __builtin_amdgcn_sqrtf(dx * dx + dy * dy + dz * dz);
            int sep = abs(resi0 - resj);
            int k = min(max(sep - 1, 0), 5);
            int d0i = min((int)dist, 19);
            float alpha = dist - (float)d0i;
            int gi = k * KSTRIDE + tib0 + jb + d0i;
            float e0 = pot[gi], e1 = pot[gi + 1];
            float val = __builtin_fmaf(alpha, e1 - e0, e0) - 2.7f;
            bool valid = (sep > 2) && (dist < 20.0f);
            if (DIAG) valid = valid && (q > p0);
            acc0 += valid ? val : 0.0f;
        }
        {
            float dx = m1.x - ox, dy = m1.y - oy, dz = m1.z - oz;
            float dist = __builtin_amdgcn_sqrtf(dx * dx + dy * dy + dz * dz);
            int sep = abs(resi1 - resj);
            int k = min(max(sep - 1, 0), 5);
            int d0i = min((int)dist, 19);
            float alpha = dist - (float)d0i;
            int gi = k * KSTRIDE + tib1 + jb + d0i;
            float e0 = pot[gi], e1 = pot[gi + 1];
            float val = __builtin_fmaf(alpha, e1 - e0, e0) - 2.7f;
            bool valid = (sep > 2) && (dist < 20.0f);
            if (DIAG) valid = valid && (q > p1);
            acc1 += valid ? val : 0.0f;
        }
    }
}

__global__ __launch_bounds__(PTHREADS) void pair_kernel(const float4* __restrict__ sorted,
                                                        const float* __restrict__ pot,
                                                        int n, int nt,
                                                        float* __restrict__ out) {
    __shared__ float pot_s[6 * MAXSLOTS * D_BINS];   // 18.1 KB
    __shared__ float wsum[PTHREADS / 64];

    int b = blockIdx.x;
    int bi = (int)((2.0 * nt + 1.0 -
                    sqrt((2.0 * nt + 1.0) * (2.0 * nt + 1.0) - 8.0 * (double)b)) * 0.5);
    if (bi < 0) bi = 0;
    if (bi > nt - 1) bi = nt - 1;
    while ((bi + 1) * nt - ((bi + 1) * bi) / 2 <= b) ++bi;
    while (bi * nt - (bi * (bi - 1)) / 2 > b) --bi;
    int bj = bi + (b - (bi * nt - (bi * (bi - 1)) / 2));

    int tid = threadIdx.x;
    int lane = tid & 63;
    int jc = tid >> 6;
    int i0 = bi * TILE, q0 = bj * TILE;

    int ihi = min(i0 + TILE, n) - 1;
    int jhi = min(q0 + TILE, n) - 1;
    int tloi = min(__float_as_int(sorted[i0].w) & 127, 84);
    int thii = min(__float_as_int(sorted[ihi].w) & 127, 84);
    int tloj = min(__float_as_int(sorted[q0].w) & 127, 84);
    int thij = min(__float_as_int(sorted[jhi].w) & 127, 84);
    int nti = thii - tloi + 1;
    int ntj = thij - tloj + 1;
    int slots = nti * ntj;
    int slots21 = slots * D_BINS;
    bool staged = (slots <= MAXSLOTS);

    if (staged) {
        int total = 6 * slots21;
        for (int e = tid; e < total; e += PTHREADS) {
            int d = e % D_BINS;
            int s2 = e / D_BINS;
            int slot = s2 % slots;
            int k = s2 / slots;
            int tii = slot / ntj;
            int tjj = slot - tii * ntj;
            pot_s[e] = pot[k * KSTRIDE + (tloi + tii) * TSTRIDE + (tloj + tjj) * D_BINS + d];
        }
    }

    int jbase = q0 + jc * 16;
    int jl = jbase + (lane & 15);
    float4 jreg;
    if (jl < n) jreg = sorted[jl];
    else { jreg.x = 3.0e7f; jreg.y = 0.f; jreg.z = 0.f; jreg.w = __int_as_float(84); }

    int p0 = i0 + lane;
    int p1 = i0 + 64 + lane;
    float4 m0, m1;
    if (p0 < n) m0 = sorted[p0];
    else { m0.x = 2.0e7f; m0.y = 0.f; m0.z = 0.f; m0.w = __int_as_float(84); }
    if (p1 < n) m1 = sorted[p1];
    else { m1.x = 2.5e7f; m1.y = 0.f; m1.z = 0.f; m1.w = __int_as_float(84); }

    int pk0 = __float_as_int(m0.w), pk1 = __float_as_int(m1.w);
    int key0 = pk0 & 127, key1 = pk1 & 127;
    int resi0 = pk0 >> 7, resi1 = pk1 >> 7;
    int islot0 = min(max(key0 - tloi, 0), nti - 1);
    int islot1 = min(max(key1 - tloi, 0), nti - 1);
    int sb21_0 = islot0 * ntj * D_BINS;
    int sb21_1 = islot1 * ntj * D_BINS;
    int tib0 = min(key0, 84) * TSTRIDE;
    int tib1 = min(key1, 84) * TSTRIDE;

    __syncthreads();

    float acc0 = 0.f, acc1 = 0.f;
    if (staged) {
        if (bi == bj)
            pair_body<true>(jreg, m0, m1, pot_s, resi0, resi1, sb21_0, sb21_1,
                            slots21, tloj, ntj, jbase, p0, p1, acc0, acc1);
        else
            pair_body<false>(jreg, m0, m1, pot_s, resi0, resi1, sb21_0, sb21_1,
                             slots21, tloj, ntj, jbase, p0, p1, acc0, acc1);
    } else {
        if (bi == bj)
            pair_body_global<true>(jreg, m0, m1, pot, resi0, resi1, tib0, tib1,
                                   jbase, p0, p1, acc0, acc1);
        else
            pair_body_global<false>(jreg, m0, m1, pot, resi0, resi1, tib0, tib1,
                                    jbase, p0, p1, acc0, acc1);
    }

    float acc = acc0 + acc1;
#pragma unroll
    for (int off = 32; off > 0; off >>= 1)
        acc += __shfl_down(acc, off, 64);
    int wave = tid >> 6;
    if (lane == 0) wsum[wave] = acc;
    __syncthreads();
    if (tid == 0) {
        float s = 0.f;
#pragma unroll
        for (int w = 0; w < PTHREADS / 64; ++w) s += wsum[w];
        atomicAdd(out, s);
    }
}

extern "C" void kernel_launch(void* const* d_in, const int* in_sizes, int n_in,
                              void* d_out, int out_size, void* d_ws, size_t ws_size,
                              hipStream_t stream) {
    const float* coords = (const float*)d_in[0];
    const int* res_ids = (const int*)d_in[1];
    const int* types   = (const int*)d_in[2];
    const float* pot   = (const float*)d_in[3];
    int n = in_sizes[1];
    float* out = (float*)d_out;

    int* hist = (int*)d_ws;
    int* counters = hist + NKEYS;
    float4* sorted = (float4*)((char*)d_ws + 1024);

    hipMemsetAsync(d_ws, 0, 1024, stream);
    hipMemsetAsync(d_out, 0, sizeof(float), stream);

    int nb = (n + 255) / 256;
    hist_kernel<<<nb, 256, 0, stream>>>(types, n, hist);
    scatter_kernel<<<nb, 256, 0, stream>>>(coords, res_ids, types, n, hist, counters, sorted);

    int nt = (n + TILE - 1) / TILE;
    int nblocks = nt * (nt + 1) / 2;
    pair_kernel<<<nblocks, PTHREADS, 0, stream>>>(sorted, pot, n, nt, out);
}

// Round 7
// 92.915 us; speedup vs baseline: 1.1060x; 1.1060x over previous
//
#include <hip/hip_runtime.h>

// RASP pairwise score, N=6144, P = N(N-1)/2.
// R7: parallel 24-block counting sort in ONE dispatch via flag-based device
// barrier (24 blocks <= 256 CUs => co-resident => spin-safe). Rank within
// block from LDS atomicAdd return (stability unnecessary: any bijection gives
// the same pair set). Pair kernel identical to R4 (known correct):
// wave holds 16 j-atoms in lanes 0..15, v_readlane broadcast, 2 i-atoms per
// thread, pot slice staged in LDS, diagonal tiles templated.

#define T_TYPES 85
#define D_BINS 21
#define TSTRIDE (T_TYPES * D_BINS)            // 1785
#define KSTRIDE (T_TYPES * T_TYPES * D_BINS)  // 151725
#define INVALID_KEY 85
#define NKEYS 86
#define TILE 128
#define PTHREADS 512
#define MAXSLOTS 36
#define SCHUNK 256
#define MAGIC 0x5AD0BEEF

// ws layout:
//   [0)        int flags[32]      (barrier flags; poison != MAGIC)
//   [256)      int hm[nsb][86]    (per-block hists, fully written)
//   [16384)    float4 sorted[n]

__global__ __launch_bounds__(SCHUNK) void sort_kernel(
    const float* __restrict__ coords, const int* __restrict__ res_ids,
    const int* __restrict__ types, int n, int nsb,
    int* __restrict__ flags, int* __restrict__ hm_g,
    float4* __restrict__ sorted, float* __restrict__ out) {

    __shared__ int lhist[NKEYS];
    __shared__ int tot_s[NKEYS];
    __shared__ int pb_s[NKEYS];
    __shared__ int cb_s[NKEYS];

    int b = blockIdx.x;
    int tid = threadIdx.x;
    int myi = b * SCHUNK + tid;

    if (tid < NKEYS) lhist[tid] = 0;
    __syncthreads();

    int mykey = INVALID_KEY, myrank = 0, myres = 0;
    bool live = (myi < n);
    if (live) {
        int t = types[myi];
        mykey = (t < 0) ? INVALID_KEY : t;
        myres = res_ids[myi];
        myrank = atomicAdd(&lhist[mykey], 1);   // within-block index (any order ok)
    }
    __syncthreads();
    if (tid < NKEYS) hm_g[b * NKEYS + tid] = lhist[tid];
    if (b == 0 && tid == 0) *out = 0.0f;
    __threadfence();                             // device-scope visibility
    __syncthreads();
    if (tid == 0) atomicExch(&flags[b], MAGIC);

    // device barrier: wait for all nsb blocks' hists
    if (tid < nsb) {
        while (atomicAdd(&flags[tid], 0) != MAGIC) { }
    }
    __syncthreads();

    // per-block re-derivation of bases (24x86 ints from L2 — cheap)
    if (tid < NKEYS) {
        int tot = 0, pb = 0;
        for (int bb = 0; bb < nsb; ++bb) {
            int v = hm_g[bb * NKEYS + tid];
            tot += v;
            if (bb < b) pb += v;
        }
        tot_s[tid] = tot;
        pb_s[tid] = pb;
    }
    __syncthreads();
    if (tid == 0) {
        int s = 0;
        for (int k = 0; k < NKEYS; ++k) { cb_s[k] = s; s += tot_s[k]; }
    }
    __syncthreads();

    if (live) {
        int pos = cb_s[mykey] + pb_s[mykey] + myrank;
        float4 v;
        if (mykey == INVALID_KEY) {
            v.x = 1.0e6f + 1000.0f * (float)pos;   // poison: dist >> 20 always
            v.y = 0.0f; v.z = 0.0f;
            v.w = __int_as_float((myres << 7) | 84);
        } else {
            v.x = coords[3 * myi + 0];
            v.y = coords[3 * myi + 1];
            v.z = coords[3 * myi + 2];
            v.w = __int_as_float((myres << 7) | mykey);
        }
        sorted[pos] = v;
    }
}

__device__ __forceinline__ float bcastf(float v, int u) {
    return __int_as_float(__builtin_amdgcn_readlane(__float_as_int(v), u));
}

template <bool DIAG>
__device__ __forceinline__ void pair_body(const float4& jreg, const float4& m0, const float4& m1,
                                          const float* __restrict__ pot_s,
                                          int resi0, int resi1, int sb21_0, int sb21_1,
                                          int slots21, int tloj, int ntj,
                                          int jbase, int p0, int p1,
                                          float& acc0, float& acc1) {
#pragma unroll
    for (int u = 0; u < 16; ++u) {
        float ox = bcastf(jreg.x, u);
        float oy = bcastf(jreg.y, u);
        float oz = bcastf(jreg.z, u);
        int pw = __builtin_amdgcn_readlane(__float_as_int(jreg.w), u);
        int keyj = pw & 127;
        int resj = pw >> 7;
        int jslot = min(max(keyj - tloj, 0), ntj - 1);
        int jb = jslot * D_BINS;
        int q = jbase + u;
        {
            float dx = m0.x - ox, dy = m0.y - oy, dz = m0.z - oz;
            float dist = __builtin_amdgcn_sqrtf(dx * dx + dy * dy + dz * dz);
            int sep = abs(resi0 - resj);
            int k = min(max(sep - 1, 0), 5);
            int d0i = min((int)dist, 19);
            float alpha = dist - (float)d0i;
            int li = k * slots21 + sb21_0 + jb + d0i;
            float e0 = pot_s[li];
            float e1 = pot_s[li + 1];
            float val = __builtin_fmaf(alpha, e1 - e0, e0) - 2.7f;
            bool valid = (sep > 2) && (dist < 20.0f);
            if (DIAG) valid = valid && (q > p0);
            acc0 += valid ? val : 0.0f;
        }
        {
            float dx = m1.x - ox, dy = m1.y - oy, dz = m1.z - oz;
            float dist = __builtin_amdgcn_sqrtf(dx * dx + dy * dy + dz * dz);
            int sep = abs(resi1 - resj);
            int k = min(max(sep - 1, 0), 5);
            int d0i = min((int)dist, 19);
            float alpha = dist - (float)d0i;
            int li = k * slots21 + sb21_1 + jb + d0i;
            float e0 = pot_s[li];
            float e1 = pot_s[li + 1];
            float val = __builtin_fmaf(alpha, e1 - e0, e0) - 2.7f;
            bool valid = (sep > 2) && (dist < 20.0f);
            if (DIAG) valid = valid && (q > p1);
            acc1 += valid ? val : 0.0f;
        }
    }
}

template <bool DIAG>
__device__ __forceinline__ void pair_body_global(const float4& jreg, const float4& m0, const float4& m1,
                                                 const float* __restrict__ pot,
                                                 int resi0, int resi1, int tib0, int tib1,
                                                 int jbase, int p0, int p1,
                                                 float& acc0, float& acc1) {
#pragma unroll
    for (int u = 0; u < 16; ++u) {
        float ox = bcastf(jreg.x, u);
        float oy = bcastf(jreg.y, u);
        float oz = bcastf(jreg.z, u);
        int pw = __builtin_amdgcn_readlane(__float_as_int(jreg.w), u);
        int keyj = min(pw & 127, 84);
        int resj = pw >> 7;
        int jb = keyj * D_BINS;
        int q = jbase + u;
        {
            float dx = m0.x - ox, dy = m0.y - oy, dz = m0.z - oz;
            float dist = __builtin_amdgcn_sqrtf(dx * dx + dy * dy + dz * dz);
            int sep = abs(resi0 - resj);
            int k = min(max(sep - 1, 0), 5);
            int d0i = min((int)dist, 19);
            float alpha = dist - (float)d0i;
            int gi = k * KSTRIDE + tib0 + jb + d0i;
            float e0 = pot[gi], e1 = pot[gi + 1];
            float val = __builtin_fmaf(alpha, e1 - e0, e0) - 2.7f;
            bool valid = (sep > 2) && (dist < 20.0f);
            if (DIAG) valid = valid && (q > p0);
            acc0 += valid ? val : 0.0f;
        }
        {
            float dx = m1.x - ox, dy = m1.y - oy, dz = m1.z - oz;
            float dist = __builtin_amdgcn_sqrtf(dx * dx + dy * dy + dz * dz);
            int sep = abs(resi1 - resj);
            int k = min(max(sep - 1, 0), 5);
            int d0i = min((int)dist, 19);
            float alpha = dist - (float)d0i;
            int gi = k * KSTRIDE + tib1 + jb + d0i;
            float e0 = pot[gi], e1 = pot[gi + 1];
            float val = __builtin_fmaf(alpha, e1 - e0, e0) - 2.7f;
            bool valid = (sep > 2) && (dist < 20.0f);
            if (DIAG) valid = valid && (q > p1);
            acc1 += valid ? val : 0.0f;
        }
    }
}

__global__ __launch_bounds__(PTHREADS) void pair_kernel(const float4* __restrict__ sorted,
                                                        const float* __restrict__ pot,
                                                        int n, int nt,
                                                        float* __restrict__ out) {
    __shared__ float pot_s[6 * MAXSLOTS * D_BINS];   // 18.1 KB
    __shared__ float wsum[PTHREADS / 64];

    int b = blockIdx.x;
    int bi = (int)((2.0 * nt + 1.0 -
                    sqrt((2.0 * nt + 1.0) * (2.0 * nt + 1.0) - 8.0 * (double)b)) * 0.5);
    if (bi < 0) bi = 0;
    if (bi > nt - 1) bi = nt - 1;
    while ((bi + 1) * nt - ((bi + 1) * bi) / 2 <= b) ++bi;
    while (bi * nt - (bi * (bi - 1)) / 2 > b) --bi;
    int bj = bi + (b - (bi * nt - (bi * (bi - 1)) / 2));

    int tid = threadIdx.x;
    int lane = tid & 63;
    int jc = tid >> 6;
    int i0 = bi * TILE, q0 = bj * TILE;

    int ihi = min(i0 + TILE, n) - 1;
    int jhi = min(q0 + TILE, n) - 1;
    int tloi = min(__float_as_int(sorted[i0].w) & 127, 84);
    int thii = min(__float_as_int(sorted[ihi].w) & 127, 84);
    int tloj = min(__float_as_int(sorted[q0].w) & 127, 84);
    int thij = min(__float_as_int(sorted[jhi].w) & 127, 84);
    int nti = thii - tloi + 1;
    int ntj = thij - tloj + 1;
    int slots = nti * ntj;
    int slots21 = slots * D_BINS;
    bool staged = (slots <= MAXSLOTS);

    if (staged) {
        int total = 6 * slots21;
        for (int e = tid; e < total; e += PTHREADS) {
            int d = e % D_BINS;
            int s2 = e / D_BINS;
            int slot = s2 % slots;
            int k = s2 / slots;
            int tii = slot / ntj;
            int tjj = slot - tii * ntj;
            pot_s[e] = pot[k * KSTRIDE + (tloi + tii) * TSTRIDE + (tloj + tjj) * D_BINS + d];
        }
    }

    int jbase = q0 + jc * 16;
    int jl = jbase + (lane & 15);
    float4 jreg;
    if (jl < n) jreg = sorted[jl];
    else { jreg.x = 3.0e7f; jreg.y = 0.f; jreg.z = 0.f; jreg.w = __int_as_float(84); }

    int p0 = i0 + lane;
    int p1 = i0 + 64 + lane;
    float4 m0, m1;
    if (p0 < n) m0 = sorted[p0];
    else { m0.x = 2.0e7f; m0.y = 0.f; m0.z = 0.f; m0.w = __int_as_float(84); }
    if (p1 < n) m1 = sorted[p1];
    else { m1.x = 2.5e7f; m1.y = 0.f; m1.z = 0.f; m1.w = __int_as_float(84); }

    int pk0 = __float_as_int(m0.w), pk1 = __float_as_int(m1.w);
    int key0 = pk0 & 127, key1 = pk1 & 127;
    int resi0 = pk0 >> 7, resi1 = pk1 >> 7;
    int islot0 = min(max(key0 - tloi, 0), nti - 1);
    int islot1 = min(max(key1 - tloi, 0), nti - 1);
    int sb21_0 = islot0 * ntj * D_BINS;
    int sb21_1 = islot1 * ntj * D_BINS;
    int tib0 = min(key0, 84) * TSTRIDE;
    int tib1 = min(key1, 84) * TSTRIDE;

    __syncthreads();

    float acc0 = 0.f, acc1 = 0.f;
    if (staged) {
        if (bi == bj)
            pair_body<true>(jreg, m0, m1, pot_s, resi0, resi1, sb21_0, sb21_1,
                            slots21, tloj, ntj, jbase, p0, p1, acc0, acc1);
        else
            pair_body<false>(jreg, m0, m1, pot_s, resi0, resi1, sb21_0, sb21_1,
                             slots21, tloj, ntj, jbase, p0, p1, acc0, acc1);
    } else {
        if (bi == bj)
            pair_body_global<true>(jreg, m0, m1, pot, resi0, resi1, tib0, tib1,
                                   jbase, p0, p1, acc0, acc1);
        else
            pair_body_global<false>(jreg, m0, m1, pot, resi0, resi1, tib0, tib1,
                                    jbase, p0, p1, acc0, acc1);
    }

    float acc = acc0 + acc1;
#pragma unroll
    for (int off = 32; off > 0; off >>= 1)
        acc += __shfl_down(acc, off, 64);
    int wave = tid >> 6;
    if (lane == 0) wsum[wave] = acc;
    __syncthreads();
    if (tid == 0) {
        float s = 0.f;
#pragma unroll
        for (int w = 0; w < PTHREADS / 64; ++w) s += wsum[w];
        atomicAdd(out, s);
    }
}

extern "C" void kernel_launch(void* const* d_in, const int* in_sizes, int n_in,
                              void* d_out, int out_size, void* d_ws, size_t ws_size,
                              hipStream_t stream) {
    const float* coords = (const float*)d_in[0];
    const int* res_ids = (const int*)d_in[1];
    const int* types   = (const int*)d_in[2];
    const float* pot   = (const float*)d_in[3];
    int n = in_sizes[1];
    float* out = (float*)d_out;

    int* flags = (int*)d_ws;
    int* hm_g = (int*)((char*)d_ws + 256);
    float4* sorted = (float4*)((char*)d_ws + 16384);

    int nsb = (n + SCHUNK - 1) / SCHUNK;   // 24
    sort_kernel<<<nsb, SCHUNK, 0, stream>>>(coords, res_ids, types, n, nsb,
                                            flags, hm_g, sorted, out);

    int nt = (n + TILE - 1) / TILE;
    int nblocks = nt * (nt + 1) / 2;
    pair_kernel<<<nblocks, PTHREADS, 0, stream>>>(sorted, pot, n, nt, out);
}